// Round 6
// baseline (12977.904 us; speedup 1.0000x reference)
//
#include <hip/hip_runtime.h>
#include <stdint.h>

#define B_    32
#define S_    1024
#define HIN   1024
#define NBLK  64
#define DBLK  16
#define HOUT  1024
#define NGATE 1152   // 64 i + 64 o + 1024 g
#define NSLICE 32    // gate slices (32 Ug rows + 2 Ui + 2 Uo each)

typedef __attribute__((ext_vector_type(8))) __bf16 bf16x8;
typedef __attribute__((ext_vector_type(4))) float  f32x4;

__device__ __forceinline__ unsigned short f2bf(float f) {
    union { float f; unsigned u; } v; v.f = f;
    return (unsigned short)((v.u + 0x7fffu + ((v.u >> 16) & 1u)) >> 16);
}
__device__ __forceinline__ float bf2f(unsigned short h) {
    union { unsigned u; float f; } v; v.u = ((unsigned)h) << 16; return v.f;
}
// fp32 -> hi+lo bf16 (v ~= hi + lo, residual <= 2^-18 |v|)
__device__ __forceinline__ void split1(float f, unsigned short& hi, unsigned short& lo) {
    hi = f2bf(f);
    lo = f2bf(f - bf2f(hi));
}

// gate-row mapping for a slice: rows 0..31 = Ug[slice*32+r], 32..33 = Ui[2s..], 34..35 = Uo[2s..]
__device__ __forceinline__ int slice_row(int slice, int r) {
    return (r < 32) ? (128 + slice * 32 + r)
         : (r < 34) ? (slice * 2 + (r - 32))
                    : (64 + slice * 2 + (r - 34));
}

// ---------------- phase 0: split W, U, h0 into hi/lo bf16 planes ----------------
__global__ void k_init(const float* __restrict__ Wi, const float* __restrict__ Wo,
                       const float* __restrict__ Wg,
                       const float* __restrict__ Ui, const float* __restrict__ Uo,
                       const float* __restrict__ Ug, const float* __restrict__ h0,
                       unsigned short* __restrict__ WsH, unsigned short* __restrict__ WsL,
                       unsigned short* __restrict__ UsH, unsigned short* __restrict__ UsL,
                       unsigned short* __restrict__ hbH, unsigned short* __restrict__ hbL)
{
    int idx = blockIdx.x * 256 + threadIdx.x;
    const int nW = NGATE * HOUT / 4;           // 294912 quads per matrix set
    float4 v; unsigned short *dH, *dL;
    if (idx < nW) {
        int f = idx * 4; int row = f >> 10, k = f & 1023;
        const float* src = (row < 64)  ? (Wi + (size_t)row * HIN)
                         : (row < 128) ? (Wo + (size_t)(row - 64) * HIN)
                                       : (Wg + (size_t)(row - 128) * HIN);
        v = *(const float4*)(src + k);
        dH = WsH + f; dL = WsL + f;
    } else if (idx < 2 * nW) {
        int f = (idx - nW) * 4; int row = f >> 10, k = f & 1023;
        const float* src = (row < 64)  ? (Ui + (size_t)row * HOUT)
                         : (row < 128) ? (Uo + (size_t)(row - 64) * HOUT)
                                       : (Ug + (size_t)(row - 128) * HOUT);
        v = *(const float4*)(src + k);
        dH = UsH + f; dL = UsL + f;
    } else {
        int f = (idx - 2 * nW) * 4;
        if (f >= B_ * HOUT) return;
        v = *(const float4*)(h0 + f);
        dH = hbH + f; dL = hbL + f;            // slot 0
    }
    unsigned short th[4], tl[4];
    split1(v.x, th[0], tl[0]); split1(v.y, th[1], tl[1]);
    split1(v.z, th[2], tl[2]); split1(v.w, th[3], tl[3]);
    *(uint2*)dH = *(const uint2*)th;
    *(uint2*)dL = *(const uint2*)tl;
}

// ---------------- phase 1: gate pre-projection GEMM (bf16x3) ----------------
#define BM 128
#define BN 128
#define BK 32
#define LDP 56

__global__ __launch_bounds__(256) void k_gates(
    const float* __restrict__ x,
    const unsigned short* __restrict__ WsH, const unsigned short* __restrict__ WsL,
    const float* __restrict__ bi, const float* __restrict__ bo, const float* __restrict__ bg,
    float* __restrict__ c_out, float* __restrict__ h_out)
{
    __shared__ unsigned short AlH[BM][LDP], AlL[BM][LDP];
    __shared__ unsigned short BlH[BN][LDP], BlL[BN][LDP];
    const int tid  = threadIdx.x;
    const int bm   = blockIdx.x, bn = blockIdx.y;
    const int wave = tid >> 6,  lane = tid & 63;
    const int l15  = lane & 15, l4 = lane >> 4;
    const int wm   = wave >> 1, wn = wave & 1;
    const int rbase = tid >> 3;          // 0..31
    const int c4    = (tid & 7) * 4;     // 0..28

    f32x4 acc[4][4] = {};

    for (int kk = 0; kk < HIN; kk += BK) {
        #pragma unroll
        for (int i = 0; i < 4; ++i) {
            int row = rbase + 32 * i;
            float4 v = *(const float4*)(x + (size_t)(bm * BM + row) * HIN + kk + c4);
            unsigned short th[4], tl[4];
            split1(v.x, th[0], tl[0]); split1(v.y, th[1], tl[1]);
            split1(v.z, th[2], tl[2]); split1(v.w, th[3], tl[3]);
            *(uint2*)&AlH[row][c4] = *(const uint2*)th;
            *(uint2*)&AlL[row][c4] = *(const uint2*)tl;
            int n = bn * BN + row;
            *(uint2*)&BlH[row][c4] = *(const uint2*)(WsH + (size_t)n * HIN + kk + c4);
            *(uint2*)&BlL[row][c4] = *(const uint2*)(WsL + (size_t)n * HIN + kk + c4);
        }
        __syncthreads();
        uint4 ah[4], al[4], bh4[4], bl4[4];
        #pragma unroll
        for (int mi = 0; mi < 4; ++mi) {
            ah[mi] = *(const uint4*)&AlH[wm * 64 + mi * 16 + l15][l4 * 8];
            al[mi] = *(const uint4*)&AlL[wm * 64 + mi * 16 + l15][l4 * 8];
        }
        #pragma unroll
        for (int ni = 0; ni < 4; ++ni) {
            bh4[ni] = *(const uint4*)&BlH[wn * 64 + ni * 16 + l15][l4 * 8];
            bl4[ni] = *(const uint4*)&BlL[wn * 64 + ni * 16 + l15][l4 * 8];
        }
        #pragma unroll
        for (int mi = 0; mi < 4; ++mi) {
            #pragma unroll
            for (int ni = 0; ni < 4; ++ni) {
                acc[mi][ni] = __builtin_amdgcn_mfma_f32_16x16x32_bf16(
                    __builtin_bit_cast(bf16x8, ah[mi]), __builtin_bit_cast(bf16x8, bh4[ni]),
                    acc[mi][ni], 0, 0, 0);
                acc[mi][ni] = __builtin_amdgcn_mfma_f32_16x16x32_bf16(
                    __builtin_bit_cast(bf16x8, ah[mi]), __builtin_bit_cast(bf16x8, bl4[ni]),
                    acc[mi][ni], 0, 0, 0);
                acc[mi][ni] = __builtin_amdgcn_mfma_f32_16x16x32_bf16(
                    __builtin_bit_cast(bf16x8, al[mi]), __builtin_bit_cast(bf16x8, bh4[ni]),
                    acc[mi][ni], 0, 0, 0);
            }
        }
        __syncthreads();
    }

    #pragma unroll
    for (int ni = 0; ni < 4; ++ni) {
        int n = bn * BN + wn * 64 + ni * 16 + l15;
        float bv = (n < 64) ? bi[n] : (n < 128) ? bo[n - 64] : bg[n - 128];
        #pragma unroll
        for (int mi = 0; mi < 4; ++mi) {
            #pragma unroll
            for (int r = 0; r < 4; ++r) {
                int m = bm * BM + wm * 64 + mi * 16 + l4 * 4 + r;
                float val = acc[mi][ni][r] + bv;
                if (n >= 128) {
                    h_out[(size_t)m * HOUT + (n - 128)] = val;
                } else if (n < 64) {
                    c_out[((size_t)m * NBLK + n) * DBLK + 0] = val;
                } else {
                    c_out[((size_t)m * NBLK + (n - 64)) * DBLK + 1] = val;
                }
            }
        }
    }
}

// ---------------- phase 2: persistent lockstep recurrence (bf16x3) ----------------
// 64 WGs x 512 thr (8 waves). slice = bid&31 owns gate rows; group = bid>>5 owns
// batches [16g,+16). Wave w owns K-chunk [128w,+128): hi+lo weight fragments pinned
// in 96 VGPRs (asm-fenced so the compiler cannot rematerialize the loads -- the
// round-5 regression); A-fragments loaded DIRECTLY from LLC. Partials combined via
// ds_add_f32 into double-buffered pre[2][16][52]. Per-wave poll of 4 producers.
__global__ __launch_bounds__(512, 1) void k_rec(
    const float* __restrict__ c0,
    float* __restrict__ c_out, float* __restrict__ h_out,
    const unsigned short* __restrict__ UsH, const unsigned short* __restrict__ UsL,
    unsigned short* __restrict__ hbH, unsigned short* __restrict__ hbL,
    unsigned int* __restrict__ flags)
{
    __shared__ float pre[2][16][52];   // pad 52: ds_add <=2-way, epilogue reads 2-way

    const int tid   = threadIdx.x;
    const int slice = blockIdx.x & 31;
    const int group = blockIdx.x >> 5;     // 0 or 1
    const int wave  = tid >> 6, lane = tid & 63;
    const int l15   = lane & 15, l4 = lane >> 4;

    // ---- pin hi+lo weight B-fragments for this wave's K-chunk (24 uint4 = 96 VGPR)
    uint4 bwh[3][4], bwl[3][4];
    #pragma unroll
    for (int nt = 0; nt < 3; ++nt) {
        int grow = nt * 16 + l15;
        bool valid = grow < 36;
        int srow = valid ? slice_row(slice, grow) : 0;
        const unsigned short* ph = UsH + (size_t)srow * HOUT + wave * 128 + l4 * 8;
        const unsigned short* pl = UsL + (size_t)srow * HOUT + wave * 128 + l4 * 8;
        #pragma unroll
        for (int ks = 0; ks < 4; ++ks) {
            bwh[nt][ks] = valid ? *(const uint4*)(ph + ks * 32) : make_uint4(0, 0, 0, 0);
            bwl[nt][ks] = valid ? *(const uint4*)(pl + ks * 32) : make_uint4(0, 0, 0, 0);
        }
    }
    // opaque fence: values can no longer be rematerialized by re-loading; they must
    // stay resident in VGPRs across the whole step loop (round-5 fix).
    #pragma unroll
    for (int nt = 0; nt < 3; ++nt) {
        #pragma unroll
        for (int ks = 0; ks < 4; ++ks) {
            asm volatile("" : "+v"(bwh[nt][ks].x), "+v"(bwh[nt][ks].y),
                              "+v"(bwh[nt][ks].z), "+v"(bwh[nt][ks].w));
            asm volatile("" : "+v"(bwl[nt][ks].x), "+v"(bwl[nt][ks].y),
                              "+v"(bwl[nt][ks].z), "+v"(bwl[nt][ks].w));
        }
    }

    // ---- per-thread epilogue mapping: 1 h-col
    const int bl   = tid >> 5;            // 0..15 batch-in-group
    const int col  = tid & 31;            // 0..31 col-in-slice
    const int Bg   = group * 16 + bl;
    const int hcol = slice * 32 + col;
    const int blkI = hcol >> 4, d0 = hcol & 15;
    float cr = c0[((size_t)Bg * NBLK + blkI) * DBLK + d0];

    unsigned int* flagbase = flags + (size_t)group * NSLICE * 32;
    unsigned int* myflag   = flagbase + slice * 32;                   // 128B apart
    unsigned int* rdflag   = flagbase + (wave * 4 + (lane & 3)) * 32; // my 4 producers

    for (int i = tid; i < 2 * 16 * 52; i += 512)
        (&pre[0][0][0])[i] = 0.f;
    __syncthreads();

    for (int t = 0; t < S_; ++t) {
        // early loads (own-WG data from k_gates; independent of flags)
        const size_t rowoff = (size_t)Bg * S_ + t;
        float xg = h_out[rowoff * HOUT + hcol];
        float xi = c_out[(rowoff * NBLK + blkI) * DBLK + 0];
        float xo = c_out[(rowoff * NBLK + blkI) * DBLK + 1];

        // wait only for THIS wave's 4 producer slices (union over waves = full barrier)
        if (t > 0) {
            unsigned v;
            do {
                v = __hip_atomic_load(rdflag, __ATOMIC_RELAXED, __HIP_MEMORY_SCOPE_AGENT);
            } while (!__all((int)(v >= (unsigned)t)));
        }

        // ---- A-fragments straight from LLC: lane(l15,l4) = 16B of row l15
        const size_t aoff = ((size_t)(t & 1) * B_ + group * 16 + l15) * HOUT
                          + wave * 128 + l4 * 8;
        const unsigned short* hH = hbH + aoff;
        const unsigned short* hL = hbL + aoff;
        uint4 auh[4], aul[4];
        #pragma unroll
        for (int ks = 0; ks < 4; ++ks) {
            unsigned long long a0 = __hip_atomic_load(
                (const unsigned long long*)(hH + ks * 32), __ATOMIC_RELAXED, __HIP_MEMORY_SCOPE_AGENT);
            unsigned long long a1 = __hip_atomic_load(
                (const unsigned long long*)(hH + ks * 32 + 4), __ATOMIC_RELAXED, __HIP_MEMORY_SCOPE_AGENT);
            unsigned long long b0 = __hip_atomic_load(
                (const unsigned long long*)(hL + ks * 32), __ATOMIC_RELAXED, __HIP_MEMORY_SCOPE_AGENT);
            unsigned long long b1 = __hip_atomic_load(
                (const unsigned long long*)(hL + ks * 32 + 4), __ATOMIC_RELAXED, __HIP_MEMORY_SCOPE_AGENT);
            auh[ks] = make_uint4((unsigned)a0, (unsigned)(a0 >> 32), (unsigned)a1, (unsigned)(a1 >> 32));
            aul[ks] = make_uint4((unsigned)b0, (unsigned)(b0 >> 32), (unsigned)b1, (unsigned)(b1 >> 32));
        }

        f32x4 acc[3] = {};
        #pragma unroll
        for (int ks = 0; ks < 4; ++ks) {
            #pragma unroll
            for (int nt = 0; nt < 3; ++nt) {
                acc[nt] = __builtin_amdgcn_mfma_f32_16x16x32_bf16(
                    __builtin_bit_cast(bf16x8, auh[ks]), __builtin_bit_cast(bf16x8, bwh[nt][ks]),
                    acc[nt], 0, 0, 0);
                acc[nt] = __builtin_amdgcn_mfma_f32_16x16x32_bf16(
                    __builtin_bit_cast(bf16x8, aul[ks]), __builtin_bit_cast(bf16x8, bwh[nt][ks]),
                    acc[nt], 0, 0, 0);
                acc[nt] = __builtin_amdgcn_mfma_f32_16x16x32_bf16(
                    __builtin_bit_cast(bf16x8, auh[ks]), __builtin_bit_cast(bf16x8, bwl[nt][ks]),
                    acc[nt], 0, 0, 0);
            }
        }

        // cross-wave combine: ds_add_f32 (C-frag: batch=l4*4+r, gate=nt*16+l15)
        float* pbuf = &pre[t & 1][0][0];
        #pragma unroll
        for (int nt = 0; nt < 3; ++nt) {
            #pragma unroll
            for (int r = 0; r < 4; ++r)
                unsafeAtomicAdd(pbuf + (l4 * 4 + r) * 52 + nt * 16 + l15, acc[nt][r]);
        }
        __syncthreads();   // [A] all adds visible; all 32 flags >= t (union of polls)

        float gp = pre[t & 1][bl][col] + xg;
        float ip = pre[t & 1][bl][32 + (col >> 4)] + xi;
        float op = pre[t & 1][bl][34 + (col >> 4)] + xo;

        // zero the other buffer for step t+1 (race-free: [B] separates from its adds)
        float* nbuf = &pre[(t + 1) & 1][0][0];
        for (int i = tid; i < 16 * 52; i += 512) nbuf[i] = 0.f;

        float ig = 1.f / (1.f + __expf(-ip));
        float og = 1.f / (1.f + __expf(-op));
        cr += ig * tanhf(gp);
        float hv = og * tanhf(cr);

        // publish h (hi/lo bf16, packed col-pairs) -- the inter-WG critical path
        unsigned short hh_, hl_; split1(hv, hh_, hl_);
        unsigned hh32 = hh_, hl32 = hl_;
        unsigned nhh = __shfl_down(hh32, 1);
        unsigned nhl = __shfl_down(hl32, 1);
        if ((lane & 1) == 0) {
            size_t dsto = ((size_t)((t + 1) & 1) * B_ + Bg) * HOUT + hcol;
            __hip_atomic_store((unsigned int*)(hbH + dsto), hh32 | (nhh << 16),
                               __ATOMIC_RELAXED, __HIP_MEMORY_SCOPE_AGENT);
            __hip_atomic_store((unsigned int*)(hbL + dsto), hl32 | (nhl << 16),
                               __ATOMIC_RELAXED, __HIP_MEMORY_SCOPE_AGENT);
        }
        asm volatile("s_waitcnt vmcnt(0)" ::: "memory");
        __syncthreads();   // [B] all waves' h stores acked
        if (tid == 0)
            __hip_atomic_store(myflag, (unsigned)(t + 1),
                               __ATOMIC_RELAXED, __HIP_MEMORY_SCOPE_AGENT);

        // outputs after the flag (off the critical path)
        c_out[(rowoff * NBLK + blkI) * DBLK + d0] = cr;
        h_out[rowoff * HOUT + hcol] = hv;
    }
}

// ---------------- launch ----------------
extern "C" void kernel_launch(void* const* d_in, const int* in_sizes, int n_in,
                              void* d_out, int out_size, void* d_ws, size_t ws_size,
                              hipStream_t stream) {
    const float* x  = (const float*)d_in[0];
    const float* h0 = (const float*)d_in[1];
    const float* c0 = (const float*)d_in[2];
    const float* Wi = (const float*)d_in[3];
    const float* bi = (const float*)d_in[4];
    const float* Wo = (const float*)d_in[5];
    const float* bo = (const float*)d_in[6];
    const float* Wg = (const float*)d_in[7];
    const float* bg = (const float*)d_in[8];
    const float* Ui = (const float*)d_in[9];
    const float* Uo = (const float*)d_in[10];
    const float* Ug = (const float*)d_in[11];

    float* c_out = (float*)d_out;
    float* h_out = c_out + (size_t)B_ * S_ * NBLK * DBLK;

    unsigned short* WsH  = (unsigned short*)d_ws;                    // [1152][1024]
    unsigned short* WsL  = WsH + (size_t)NGATE * HOUT;
    unsigned short* UsH  = WsL + (size_t)NGATE * HOUT;
    unsigned short* UsL  = UsH + (size_t)NGATE * HOUT;
    unsigned short* hbH  = UsL + (size_t)NGATE * HOUT;               // [2][32][1024]
    unsigned short* hbL  = hbH + (size_t)2 * B_ * HOUT;
    unsigned int*   flags = (unsigned int*)(hbL + (size_t)2 * B_ * HOUT); // 64 x 128B

    hipMemsetAsync(flags, 0, 64 * 32 * sizeof(unsigned int), stream);
    k_init<<<2336, 256, 0, stream>>>(Wi, Wo, Wg, Ui, Uo, Ug, h0, WsH, WsL, UsH, UsL, hbH, hbL);
    k_gates<<<dim3((B_ * S_) / BM, NGATE / BN), 256, 0, stream>>>(
        x, WsH, WsL, bi, bo, bg, c_out, h_out);
    k_rec<<<64, 512, 0, stream>>>(c0, c_out, h_out, UsH, UsL, hbH, hbL, flags);
}

// Round 7
// 12128.742 us; speedup vs baseline: 1.0700x; 1.0700x over previous
//
#include <hip/hip_runtime.h>
#include <stdint.h>

#define B_    32
#define S_    1024
#define HIN   1024
#define NBLK  64
#define DBLK  16
#define HOUT  1024
#define NGATE 1152   // 64 i + 64 o + 1024 g
#define NSLICE 32    // gate slices (32 Ug rows + 2 Ui + 2 Uo each)

typedef __attribute__((ext_vector_type(8))) __bf16 bf16x8;
typedef __attribute__((ext_vector_type(4))) float  f32x4;

__device__ __forceinline__ unsigned short f2bf(float f) {
    union { float f; unsigned u; } v; v.f = f;
    return (unsigned short)((v.u + 0x7fffu + ((v.u >> 16) & 1u)) >> 16);
}
__device__ __forceinline__ float bf2f(unsigned short h) {
    union { unsigned u; float f; } v; v.u = ((unsigned)h) << 16; return v.f;
}
// fp32 -> hi+lo bf16 (v ~= hi + lo, residual <= 2^-18 |v|)
__device__ __forceinline__ void split1(float f, unsigned short& hi, unsigned short& lo) {
    hi = f2bf(f);
    lo = f2bf(f - bf2f(hi));
}

// gate-row mapping for a slice: rows 0..31 = Ug[slice*32+r], 32..33 = Ui[2s..], 34..35 = Uo[2s..]
__device__ __forceinline__ int slice_row(int slice, int r) {
    return (r < 32) ? (128 + slice * 32 + r)
         : (r < 34) ? (slice * 2 + (r - 32))
                    : (64 + slice * 2 + (r - 34));
}

// ---------------- phase 0: split W,U into hi/lo bf16; copy h0 fp32 ----------------
__global__ void k_init(const float* __restrict__ Wi, const float* __restrict__ Wo,
                       const float* __restrict__ Wg,
                       const float* __restrict__ Ui, const float* __restrict__ Uo,
                       const float* __restrict__ Ug, const float* __restrict__ h0,
                       unsigned short* __restrict__ WsH, unsigned short* __restrict__ WsL,
                       unsigned short* __restrict__ UsH, unsigned short* __restrict__ UsL,
                       float* __restrict__ hb32)
{
    int idx = blockIdx.x * 256 + threadIdx.x;
    const int nW = NGATE * HOUT / 4;           // 294912 quads per matrix set
    float4 v; unsigned short *dH, *dL;
    if (idx < nW) {
        int f = idx * 4; int row = f >> 10, k = f & 1023;
        const float* src = (row < 64)  ? (Wi + (size_t)row * HIN)
                         : (row < 128) ? (Wo + (size_t)(row - 64) * HIN)
                                       : (Wg + (size_t)(row - 128) * HIN);
        v = *(const float4*)(src + k);
        dH = WsH + f; dL = WsL + f;
    } else if (idx < 2 * nW) {
        int f = (idx - nW) * 4; int row = f >> 10, k = f & 1023;
        const float* src = (row < 64)  ? (Ui + (size_t)row * HOUT)
                         : (row < 128) ? (Uo + (size_t)(row - 64) * HOUT)
                                       : (Ug + (size_t)(row - 128) * HOUT);
        v = *(const float4*)(src + k);
        dH = UsH + f; dL = UsL + f;
    } else {
        int f = (idx - 2 * nW) * 4;
        if (f >= B_ * HOUT) return;
        *(float4*)(hb32 + f) = *(const float4*)(h0 + f);   // slot 0
        return;
    }
    unsigned short th[4], tl[4];
    split1(v.x, th[0], tl[0]); split1(v.y, th[1], tl[1]);
    split1(v.z, th[2], tl[2]); split1(v.w, th[3], tl[3]);
    *(uint2*)dH = *(const uint2*)th;
    *(uint2*)dL = *(const uint2*)tl;
}

// ---------------- phase 1: gate pre-projection GEMM (bf16x3) ----------------
#define BM 128
#define BN 128
#define BK 32
#define LDP 56

__global__ __launch_bounds__(256) void k_gates(
    const float* __restrict__ x,
    const unsigned short* __restrict__ WsH, const unsigned short* __restrict__ WsL,
    const float* __restrict__ bi, const float* __restrict__ bo, const float* __restrict__ bg,
    float* __restrict__ c_out, float* __restrict__ h_out)
{
    __shared__ unsigned short AlH[BM][LDP], AlL[BM][LDP];
    __shared__ unsigned short BlH[BN][LDP], BlL[BN][LDP];
    const int tid  = threadIdx.x;
    const int bm   = blockIdx.x, bn = blockIdx.y;
    const int wave = tid >> 6,  lane = tid & 63;
    const int l15  = lane & 15, l4 = lane >> 4;
    const int wm   = wave >> 1, wn = wave & 1;
    const int rbase = tid >> 3;          // 0..31
    const int c4    = (tid & 7) * 4;     // 0..28

    f32x4 acc[4][4] = {};

    for (int kk = 0; kk < HIN; kk += BK) {
        #pragma unroll
        for (int i = 0; i < 4; ++i) {
            int row = rbase + 32 * i;
            float4 v = *(const float4*)(x + (size_t)(bm * BM + row) * HIN + kk + c4);
            unsigned short th[4], tl[4];
            split1(v.x, th[0], tl[0]); split1(v.y, th[1], tl[1]);
            split1(v.z, th[2], tl[2]); split1(v.w, th[3], tl[3]);
            *(uint2*)&AlH[row][c4] = *(const uint2*)th;
            *(uint2*)&AlL[row][c4] = *(const uint2*)tl;
            int n = bn * BN + row;
            *(uint2*)&BlH[row][c4] = *(const uint2*)(WsH + (size_t)n * HIN + kk + c4);
            *(uint2*)&BlL[row][c4] = *(const uint2*)(WsL + (size_t)n * HIN + kk + c4);
        }
        __syncthreads();
        uint4 ah[4], al[4], bh4[4], bl4[4];
        #pragma unroll
        for (int mi = 0; mi < 4; ++mi) {
            ah[mi] = *(const uint4*)&AlH[wm * 64 + mi * 16 + l15][l4 * 8];
            al[mi] = *(const uint4*)&AlL[wm * 64 + mi * 16 + l15][l4 * 8];
        }
        #pragma unroll
        for (int ni = 0; ni < 4; ++ni) {
            bh4[ni] = *(const uint4*)&BlH[wn * 64 + ni * 16 + l15][l4 * 8];
            bl4[ni] = *(const uint4*)&BlL[wn * 64 + ni * 16 + l15][l4 * 8];
        }
        #pragma unroll
        for (int mi = 0; mi < 4; ++mi) {
            #pragma unroll
            for (int ni = 0; ni < 4; ++ni) {
                acc[mi][ni] = __builtin_amdgcn_mfma_f32_16x16x32_bf16(
                    __builtin_bit_cast(bf16x8, ah[mi]), __builtin_bit_cast(bf16x8, bh4[ni]),
                    acc[mi][ni], 0, 0, 0);
                acc[mi][ni] = __builtin_amdgcn_mfma_f32_16x16x32_bf16(
                    __builtin_bit_cast(bf16x8, ah[mi]), __builtin_bit_cast(bf16x8, bl4[ni]),
                    acc[mi][ni], 0, 0, 0);
                acc[mi][ni] = __builtin_amdgcn_mfma_f32_16x16x32_bf16(
                    __builtin_bit_cast(bf16x8, al[mi]), __builtin_bit_cast(bf16x8, bh4[ni]),
                    acc[mi][ni], 0, 0, 0);
            }
        }
        __syncthreads();
    }

    #pragma unroll
    for (int ni = 0; ni < 4; ++ni) {
        int n = bn * BN + wn * 64 + ni * 16 + l15;
        float bv = (n < 64) ? bi[n] : (n < 128) ? bo[n - 64] : bg[n - 128];
        #pragma unroll
        for (int mi = 0; mi < 4; ++mi) {
            #pragma unroll
            for (int r = 0; r < 4; ++r) {
                int m = bm * BM + wm * 64 + mi * 16 + l4 * 4 + r;
                float val = acc[mi][ni][r] + bv;
                if (n >= 128) {
                    h_out[(size_t)m * HOUT + (n - 128)] = val;
                } else if (n < 64) {
                    c_out[((size_t)m * NBLK + n) * DBLK + 0] = val;
                } else {
                    c_out[((size_t)m * NBLK + (n - 64)) * DBLK + 1] = val;
                }
            }
        }
    }
}

// ---------------- phase 2: persistent lockstep recurrence (bf16x3) ----------------
// 64 WGs x 512 thr (8 waves). slice = bid&31, group = bid>>5 (batches [16g,+16)).
// Wave w owns K-chunk [128w,+128). NOTHING big is loop-invariant in registers:
//   U hi-plane: LDS (XOR-swizzled 16B units), 12 ds_read_b128/wave/step
//   U lo-plane: streamed from L1/L2 every step (12x16B plain loads/lane)
//   h: single fp32 plane in LLC; consumer splits to hi/lo bf16 in VALU
// Partials combined via ds_add into pre[2][16][52]; per-wave poll of 4 producers.
__global__ __launch_bounds__(512, 2) void k_rec(
    const float* __restrict__ c0,
    float* __restrict__ c_out, float* __restrict__ h_out,
    const unsigned short* __restrict__ UsH, const unsigned short* __restrict__ UsL,
    float* __restrict__ hb32, unsigned int* __restrict__ flags)
{
    __shared__ unsigned short Whi[37][1024];   // 74 KB, row 36 = junk pad for invalid lanes
    __shared__ float pre[2][16][52];           // 6.6 KB

    const int tid   = threadIdx.x;
    const int slice = blockIdx.x & 31;
    const int group = blockIdx.x >> 5;     // 0 or 1
    const int wave  = tid >> 6, lane = tid & 63;
    const int l15   = lane & 15, l4 = lane >> 4;

    // ---- stage U hi-plane into LDS, XOR-swizzled in 16B units: unit u -> u^(r&7)
    for (int idx = tid; idx < 36 * 128; idx += 512) {
        int r = idx >> 7, u = idx & 127;
        uint4 v = *(const uint4*)(UsH + (size_t)slice_row(slice, r) * HOUT + u * 8);
        *(uint4*)((char*)&Whi[0][0] + r * 2048 + ((u ^ (r & 7)) << 4)) = v;
    }
    for (int i = tid; i < 2 * 16 * 52; i += 512)
        (&pre[0][0][0])[i] = 0.f;

    // ---- per-(nt) fragment addressing (row clamped to pad row 36 for invalid lanes)
    int rowbyte[3], rm[3];
    const unsigned short* wlp[3];
    #pragma unroll
    for (int nt = 0; nt < 3; ++nt) {
        int grow = nt * 16 + l15;
        int r = (grow < 36) ? grow : 36;
        rowbyte[nt] = r * 2048;
        rm[nt] = r & 7;
        int srow = (grow < 36) ? slice_row(slice, grow) : 0;
        wlp[nt] = UsL + (size_t)srow * HOUT + wave * 128 + l4 * 8;
    }
    const int ubase = wave * 16 + l4;

    // ---- per-thread epilogue mapping: 1 h-col
    const int bl   = tid >> 5;            // 0..15 batch-in-group
    const int col  = tid & 31;            // 0..31 col-in-slice
    const int Bg   = group * 16 + bl;
    const int hcol = slice * 32 + col;
    const int blkI = hcol >> 4, d0 = hcol & 15;
    float cr = c0[((size_t)Bg * NBLK + blkI) * DBLK + d0];

    unsigned int* flagbase = flags + (size_t)group * NSLICE * 32;
    unsigned int* myflag   = flagbase + slice * 32;                   // 128B apart
    unsigned int* rdflag   = flagbase + (wave * 4 + (lane & 3)) * 32; // my 4 producers

    __syncthreads();   // Whi + pre ready

    for (int t = 0; t < S_; ++t) {
        // ---- issue lo-plane weight stream FIRST (L1/L2-resident, VMEM pipe)
        uint4 wl[3][4];
        #pragma unroll
        for (int nt = 0; nt < 3; ++nt)
            #pragma unroll
            for (int ks = 0; ks < 4; ++ks)
                wl[nt][ks] = *(const uint4*)(wlp[nt] + ks * 32);

        // early loads (own-WG data from k_gates; independent of flags)
        const size_t rowoff = (size_t)Bg * S_ + t;
        float xg = h_out[rowoff * HOUT + hcol];
        float xi = c_out[(rowoff * NBLK + blkI) * DBLK + 0];
        float xo = c_out[(rowoff * NBLK + blkI) * DBLK + 1];

        __builtin_amdgcn_sched_barrier(0);

        // wait only for THIS wave's 4 producer slices (union over waves = full barrier)
        if (t > 0) {
            unsigned v;
            do {
                v = __hip_atomic_load(rdflag, __ATOMIC_RELAXED, __HIP_MEMORY_SCOPE_AGENT);
            } while (!__all((int)(v >= (unsigned)t)));
        }

        // ---- h fp32 straight from LLC; split to hi/lo bf16 fragments in VALU
        const float* hrow = hb32 + ((size_t)(t & 1) * B_ + group * 16 + l15) * HOUT
                          + wave * 128 + l4 * 8;
        uint4 auh[4], aul[4];
        #pragma unroll
        for (int ks = 0; ks < 4; ++ks) {
            const unsigned long long* p = (const unsigned long long*)(hrow + ks * 32);
            unsigned uh[4], ul[4];
            #pragma unroll
            for (int j = 0; j < 4; ++j) {
                unsigned long long v = __hip_atomic_load(p + j,
                                        __ATOMIC_RELAXED, __HIP_MEMORY_SCOPE_AGENT);
                float f0 = __uint_as_float((unsigned)v);
                float f1 = __uint_as_float((unsigned)(v >> 32));
                unsigned short h0_, l0_, h1_, l1_;
                split1(f0, h0_, l0_); split1(f1, h1_, l1_);
                uh[j] = (unsigned)h0_ | ((unsigned)h1_ << 16);
                ul[j] = (unsigned)l0_ | ((unsigned)l1_ << 16);
            }
            auh[ks] = make_uint4(uh[0], uh[1], uh[2], uh[3]);
            aul[ks] = make_uint4(ul[0], ul[1], ul[2], ul[3]);
        }

        // ---- MFMA: hi-weights from LDS (swizzled), lo-weights from stream
        f32x4 acc[3] = {};
        #pragma unroll
        for (int ks = 0; ks < 4; ++ks) {
            int u = ubase + ks * 4;
            #pragma unroll
            for (int nt = 0; nt < 3; ++nt) {
                uint4 bh = *(const uint4*)((const char*)&Whi[0][0]
                              + rowbyte[nt] + ((u ^ rm[nt]) << 4));
                acc[nt] = __builtin_amdgcn_mfma_f32_16x16x32_bf16(
                    __builtin_bit_cast(bf16x8, auh[ks]), __builtin_bit_cast(bf16x8, bh),
                    acc[nt], 0, 0, 0);
                acc[nt] = __builtin_amdgcn_mfma_f32_16x16x32_bf16(
                    __builtin_bit_cast(bf16x8, aul[ks]), __builtin_bit_cast(bf16x8, bh),
                    acc[nt], 0, 0, 0);
                acc[nt] = __builtin_amdgcn_mfma_f32_16x16x32_bf16(
                    __builtin_bit_cast(bf16x8, auh[ks]), __builtin_bit_cast(bf16x8, wl[nt][ks]),
                    acc[nt], 0, 0, 0);
            }
        }

        // cross-wave combine: ds_add (C-frag: batch=l4*4+r, gate=nt*16+l15)
        float* pbuf = &pre[t & 1][0][0];
        #pragma unroll
        for (int nt = 0; nt < 3; ++nt) {
            #pragma unroll
            for (int r = 0; r < 4; ++r)
                unsafeAtomicAdd(pbuf + (l4 * 4 + r) * 52 + nt * 16 + l15, acc[nt][r]);
        }
        __syncthreads();   // [A] all adds visible

        float gp = pre[t & 1][bl][col] + xg;
        float ip = pre[t & 1][bl][32 + (col >> 4)] + xi;
        float op = pre[t & 1][bl][34 + (col >> 4)] + xo;

        // zero the other buffer for step t+1 (race-free: [B] separates from its adds)
        float* nbuf = &pre[(t + 1) & 1][0][0];
        for (int i = tid; i < 16 * 52; i += 512) nbuf[i] = 0.f;

        float ig = 1.f / (1.f + __expf(-ip));
        float og = 1.f / (1.f + __expf(-op));
        cr += ig * tanhf(gp);
        float hv = og * tanhf(cr);

        // publish h fp32 (agent-scope, LLC) -- the inter-WG critical path
        __hip_atomic_store(hb32 + ((size_t)((t + 1) & 1) * B_ + Bg) * HOUT + hcol, hv,
                           __ATOMIC_RELAXED, __HIP_MEMORY_SCOPE_AGENT);
        asm volatile("s_waitcnt vmcnt(0)" ::: "memory");
        __syncthreads();   // [B] all waves' h stores acked
        if (tid == 0)
            __hip_atomic_store(myflag, (unsigned)(t + 1),
                               __ATOMIC_RELAXED, __HIP_MEMORY_SCOPE_AGENT);

        // outputs after the flag (off the critical path)
        c_out[(rowoff * NBLK + blkI) * DBLK + d0] = cr;
        h_out[rowoff * HOUT + hcol] = hv;
    }
}

// ---------------- launch ----------------
extern "C" void kernel_launch(void* const* d_in, const int* in_sizes, int n_in,
                              void* d_out, int out_size, void* d_ws, size_t ws_size,
                              hipStream_t stream) {
    const float* x  = (const float*)d_in[0];
    const float* h0 = (const float*)d_in[1];
    const float* c0 = (const float*)d_in[2];
    const float* Wi = (const float*)d_in[3];
    const float* bi = (const float*)d_in[4];
    const float* Wo = (const float*)d_in[5];
    const float* bo = (const float*)d_in[6];
    const float* Wg = (const float*)d_in[7];
    const float* bg = (const float*)d_in[8];
    const float* Ui = (const float*)d_in[9];
    const float* Uo = (const float*)d_in[10];
    const float* Ug = (const float*)d_in[11];

    float* c_out = (float*)d_out;
    float* h_out = c_out + (size_t)B_ * S_ * NBLK * DBLK;

    unsigned short* WsH  = (unsigned short*)d_ws;                    // [1152][1024]
    unsigned short* WsL  = WsH + (size_t)NGATE * HOUT;
    unsigned short* UsH  = WsL + (size_t)NGATE * HOUT;
    unsigned short* UsL  = UsH + (size_t)NGATE * HOUT;
    float*          hb32 = (float*)(UsL + (size_t)NGATE * HOUT);     // [2][32][1024] fp32
    unsigned int*   flags = (unsigned int*)(hb32 + (size_t)2 * B_ * HOUT); // 64 x 128B

    hipMemsetAsync(flags, 0, 64 * 32 * sizeof(unsigned int), stream);
    k_init<<<2336, 256, 0, stream>>>(Wi, Wo, Wg, Ui, Uo, Ug, h0, WsH, WsL, UsH, UsL, hb32);
    k_gates<<<dim3((B_ * S_) / BM, NGATE / BN), 256, 0, stream>>>(
        x, WsH, WsL, bi, bo, bg, c_out, h_out);
    k_rec<<<64, 512, 0, stream>>>(c0, c_out, h_out, UsH, UsL, hb32, flags);
}